// Round 8
// baseline (449.140 us; speedup 1.0000x reference)
//
#include <hip/hip_runtime.h>
#include <stdint.h>

#define LDIFF 0.24f

constexpr int H = 512, W = 512, NB = 2;
constexpr int HW = H * W;              // 2^18
constexpr int N_D = NB * HW;           // 524288
constexpr int CVH = 511, CVW = 512;
constexpr int CHH = 512, CHW = 511;
constexpr int N_CV = NB * CVH * CVW;   // 523264
constexpr int NBLKS = 11;              // 11x11 blocks, step 48
constexpr int NBT = NB * 121;          // 242 workgroups <= 256 CUs -> co-resident

// LLC-coherent (cross-XCD) access: relaxed agent atomics = sc1 ops through the
// Infinity Cache. Validated R4-R6.
__device__ inline float ldc(const float* p) {
    return __hip_atomic_load(p, __ATOMIC_RELAXED, __HIP_MEMORY_SCOPE_AGENT);
}
__device__ inline void stc(float* p, float v) {
    __hip_atomic_store(p, v, __ATOMIC_RELAXED, __HIP_MEMORY_SCOPE_AGENT);
}
__device__ inline int ldci(const int* p) {
    return __hip_atomic_load(p, __ATOMIC_RELAXED, __HIP_MEMORY_SCOPE_AGENT);
}
__device__ inline void stci(int* p, int v) {
    __hip_atomic_store(p, v, __ATOMIC_RELAXED, __HIP_MEMORY_SCOPE_AGENT);
}
template <int SLP>
__device__ inline void poll_ge(const int* p, int v) {
    while (ldci(p) < v) __builtin_amdgcn_s_sleep(SLP);
}

// wave64 DPP rotations/shifts (VALU pipe, no LDS traffic). Direction probed at
// runtime (dirL); the wavefront stencil's use is direction-agnostic.
__device__ inline float rot_a(float x) {
    return __int_as_float(__builtin_amdgcn_update_dpp(0, __float_as_int(x), 0x134, 0xf, 0xf, false));
}
__device__ inline float rot_b(float x) {
    return __int_as_float(__builtin_amdgcn_update_dpp(0, __float_as_int(x), 0x13c, 0xf, 0xf, false));
}
__device__ inline float sh_a(float x) {
    return __int_as_float(__builtin_amdgcn_update_dpp(0, __float_as_int(x), 0x130, 0xf, 0xf, true));
}
__device__ inline float sh_b(float x) {
    return __int_as_float(__builtin_amdgcn_update_dpp(0, __float_as_int(x), 0x138, 0xf, 0xf, true));
}

// ======================= ONE kernel for the whole pipeline =======================
// A) cv/ch + D:=initial  B) global barrier  C) per-block params
// D) ROW-CHAINED wavefront: one worker per block-row; intra-row dep via LDS
//    strip buffer, inter-row dep via rowflag (count of completed blocks)
// E) diffusion 8 stages x 8 iters, neighbor-flag chained, pipelines behind D.
__global__ __launch_bounds__(256) void kall(
    const float* __restrict__ guide, const float* __restrict__ initial,
    float* __restrict__ cv, float* __restrict__ ch,
    float* __restrict__ D, float* __restrict__ T0, float* __restrict__ T1,
    float* __restrict__ ypred, int* __restrict__ sync_)
{
    __shared__ float pool[8712];          // cvT[4356] | chT[4356]
    __shared__ float sm[256];
    __shared__ float prmS[4];
    __shared__ float xT[4][64];
    __shared__ float xB[4][64];
    __shared__ float cvB[4][64];
    __shared__ float stripS[64][16];      // right 16-col strip of prev block (final values)
    float* cvT = pool;
    float* chT = pool + 4356;

    int* bar     = sync_;                 // [0]
    int* rowflag = sync_ + 16;            // (b*11+i)*16, 64B padded
    int* dflag   = sync_ + 512;           // (b*121+blk)*16
    int* prmq    = sync_ + 4608;          // (b*121+blk)*8 : [cvm,chm,cond,ready]

    const int blk = blockIdx.x;           // 0..120
    const int i = blk / NBLKS, j = blk % NBLKS;
    const int b = blockIdx.y;
    const int tid = threadIdx.x;
    const int lane = tid & 63, wv = tid >> 6;
    const int r0 = wv * 16;
    const int me = b * 121 + blk;

    // ===== Phase A: cv/ch (normal stores into d_out) + D := initial (sc1) =====
    const float kinv = 1.0f / (0.03f * 0.03f);
    for (int idx = me * 256 + tid; idx < N_D; idx += NBT * 256) {
        int bb = idx >> 18;
        int yx = idx & (HW - 1);
        int y = yx >> 9, x = yx & 511;
        const float* g = guide + (size_t)bb * 3 * HW + yx;
        float g0 = g[0], g1 = g[HW], g2 = g[2 * HW];
        stc(&D[idx], initial[idx]);
        if (y < 511) {
            float d = (fabsf(g[512] - g0) + fabsf(g[HW + 512] - g1) + fabsf(g[2 * HW + 512] - g2)) * (1.0f / 3.0f);
            cv[bb * CVH * CVW + y * CVW + x] = 1.0f / (1.0f + d * d * kinv);
        }
        if (x < 511) {
            float d = (fabsf(g[1] - g0) + fabsf(g[HW + 1] - g1) + fabsf(g[2 * HW + 1] - g2)) * (1.0f / 3.0f);
            ch[bb * CHH * CHW + y * CHW + x] = 1.0f / (1.0f + d * d * kinv);
        }
    }

    // ===== one-shot global barrier (release/acquire) =====
    __syncthreads();
    if (tid == 0) {
        __hip_atomic_fetch_add(bar, 1, __ATOMIC_ACQ_REL, __HIP_MEMORY_SCOPE_AGENT);
        while (ldci(bar) < NBT) __builtin_amdgcn_s_sleep(8);
    }
    __syncthreads();
    __builtin_amdgcn_fence(__ATOMIC_ACQUIRE, "agent");

    // ===== Phase C: per-block params =====
    const int y0 = i * 48, x0 = j * 48;
    const int y1 = min(y0 + 64, 512), x1 = min(x0 + 64, 512);
    const int bh = y1 - y0, bw = x1 - x0;
    const float* cvb = cv + b * CVH * CVW;
    const float* chb = ch + b * CHH * CHW;

    for (int p = tid; p < 66 * 66; p += 256) {
        int rr = p / 66, c2 = p - rr * 66;
        int y = y0 - 1 + rr, x = x0 - 1 + c2;
        cvT[p] = (y >= 0 && y < 511 && x >= 0 && x < 512) ? cvb[y * CVW + x] : 0.0f;
        chT[p] = (y >= 0 && y < 512 && x >= 0 && x < 511) ? chb[y * CHW + x] : 0.0f;
    }
    __syncthreads();

    float scv = 0.f, sch = 0.f, sun = 0.f;
    {
        int n = (bh - 1) * bw;
        for (int p = tid; p < n; p += 256) { int r = p / bw, c = p - r * bw; scv += cvT[(r + 1) * 66 + c + 1]; }
    }
    {
        int cols = bw - 1, n = bh * cols;
        for (int p = tid; p < n; p += 256) { int r = p / cols, c = p - r * cols; sch += chT[(r + 1) * 66 + c + 1]; }
    }
    const int ur = min(y1, 511) - y0, uc = min(x1, 511) - x0;
    {
        int n = ur * uc;
        for (int p = tid; p < n; p += 256) {
            int r = p / uc, c = p - r * uc;
            float s1 = 0.f, s2 = 0.f, t1 = 0.f, t2 = 0.f;
            #pragma unroll
            for (int dy = 0; dy < 3; dy++)
                #pragma unroll
                for (int dx = 0; dx < 3; dx++) {
                    float v = cvT[(r + dy) * 66 + c + dx]; s1 += v; s2 += v * v;
                    float w2 = chT[(r + dy) * 66 + c + dx]; t1 += w2; t2 += w2 * w2;
                }
            float m = s1 * (1.0f / 9.0f);
            float vcv = s2 * (1.0f / 9.0f) - m * m;
            m = t1 * (1.0f / 9.0f);
            float vch = t2 * (1.0f / 9.0f) - m * m;
            if (vcv < 0.1f && vch < 0.1f) sun += 1.f;
        }
    }
    sm[tid] = scv; __syncthreads();
    for (int s = 128; s; s >>= 1) { if (tid < s) sm[tid] += sm[tid + s]; __syncthreads(); }
    if (tid == 0) prmS[0] = sm[0] / (float)((bh - 1) * bw);
    __syncthreads();
    sm[tid] = sch; __syncthreads();
    for (int s = 128; s; s >>= 1) { if (tid < s) sm[tid] += sm[tid + s]; __syncthreads(); }
    if (tid == 0) prmS[1] = sm[0] / (float)(bh * (bw - 1));
    __syncthreads();
    sm[tid] = sun; __syncthreads();
    for (int s = 128; s; s >>= 1) { if (tid < s) sm[tid] += sm[tid + s]; __syncthreads(); }
    if (tid == 0) prmS[2] = (sm[0] / (float)(ur * uc) > 0.7f) ? 1.0f : 0.0f;
    __syncthreads();

    // DPP direction probe (wave-uniform)
    int pr = __builtin_amdgcn_update_dpp(0, lane, 0x134, 0xf, 0xf, false);
    const bool dirL = (pr == ((lane + 63) & 63));

    float* Db = D + b * HW;

    // ===== Phase D: row-chained wavefront =====
    if (j == 0) {
        const int bhR = bh;               // 64, or 32 for i==10 (replication trick)
        const int mh = bhR - 1;
        const int rfme = (b * 11 + i) * 16;
        for (int jj = 0; jj <= 10; jj++) {
            const int x0j = jj * 48;
            const int bwj = (jj == 10) ? 32 : 64;
            const int mw = bwj - 1;
            const int cc = lane & mw;
            // params: local for jj==0, mailbox otherwise
            if (jj > 0) {
                if (tid == 0) {
                    int* q = prmq + (b * 121 + i * NBLKS + jj) * 8;
                    while (ldci(&q[3]) == 0) __builtin_amdgcn_s_sleep(2);
                    prmS[0] = __int_as_float(ldci(&q[0]));
                    prmS[1] = __int_as_float(ldci(&q[1]));
                    prmS[2] = __int_as_float(ldci(&q[2]));
                }
            }
            if (i > 0 && tid == 1)
                poll_ge<2>(&rowflag[(b * 11 + i - 1) * 16], min(jj + 2, 11));
            __syncthreads();
            const bool cond = prmS[2] > 0.5f;
            const float a = LDIFF * prmS[0], bc = LDIFF * prmS[1];

            if (cond) {
                float u[16], orig[16];
                #pragma unroll
                for (int k = 0; k < 16; k++) {
                    int rr = (r0 + k) & mh;
                    orig[k] = (jj > 0 && cc < 16) ? stripS[r0 + k][cc]
                                                  : ldc(&Db[(y0 + rr) * W + x0j + cc]);
                    u[k] = orig[k];
                }
                for (int it = 0; it < 10; it++) {
                    xT[wv][lane] = u[0];
                    xB[wv][lane] = u[15];
                    __syncthreads();
                    float ub = xB[(wv + 3) & 3][lane];
                    float ut = xT[(wv + 1) & 3][lane];
                    float nu[16];
                    #pragma unroll
                    for (int k = 0; k < 16; k++) {
                        float up = (k == 0) ? ub : u[k - 1];
                        float dn = (k == 15) ? ut : u[k + 1];
                        float hsum = rot_a(u[k]) + rot_b(u[k]);
                        nu[k] = u[k] + a * (up + dn - 2.0f * u[k]) + bc * (hsum - 2.0f * u[k]);
                    }
                    #pragma unroll
                    for (int k = 0; k < 16; k++) u[k] = nu[k];
                    __syncthreads();
                }
                #pragma unroll
                for (int k = 0; k < 16; k++) {
                    int rr = (r0 + k) & mh;
                    float byw = (y0 > 0 && rr < 16) ? (float)rr * (1.0f / 16.0f) : 1.0f;
                    float bxw = (x0j > 0 && cc < 16) ? (float)cc * (1.0f / 16.0f) : 1.0f;
                    float wgt = byw * bxw;
                    float val = orig[k] * (1.0f - wgt) + u[k] * wgt;
                    if ((r0 + k) < bhR && lane < bwj)
                        stc(&Db[(y0 + r0 + k) * W + x0j + lane], val);
                    if (jj < 10 && lane >= 48) stripS[r0 + k][lane - 48] = val;
                }
            } else {
                if (jj < 10 && lane >= 48) {
                    #pragma unroll
                    for (int k = 0; k < 16; k++) {
                        int rr = (r0 + k) & mh;
                        stripS[r0 + k][lane - 48] = ldc(&Db[(y0 + rr) * W + x0j + lane]);
                    }
                }
            }
            asm volatile("s_waitcnt vmcnt(0)" ::: "memory");
            __syncthreads();
            if (tid == 0) stci(&rowflag[rfme], jj + 1);
        }
    } else {
        // publish my block's params for the row worker
        if (tid == 0) {
            int* q = prmq + me * 8;
            stci(&q[0], __float_as_int(prmS[0]));
            stci(&q[1], __float_as_int(prmS[1]));
            stci(&q[2], __float_as_int(prmS[2]));
            asm volatile("s_waitcnt vmcnt(0)" ::: "memory");
            stci(&q[3], 1);
        }
    }

    // ===== Phase E: diffusion, 8 stages x 8 iters =====
    const int gy0 = y0 - 8, gx0 = x0 - 8;
    const int cx = gx0 + lane;
    const int gxc = min(max(cx, 0), 511);
    const bool xv = (cx >= 0 && cx < 512);
    float cvr[16], chr[16], chl[16];
    int gyA[16];
    #pragma unroll
    for (int k = 0; k < 16; k++) {
        int cy = gy0 + r0 + k;
        gyA[k] = min(max(cy, 0), 511);
        cvr[k] = (cy >= 0 && cy < 511 && xv) ? cvb[cy * CVW + cx] : 0.0f;
        chr[k] = (cy >= 0 && cy < 512 && xv && cx < 511) ? chb[cy * CHW + cx] : 0.0f;
        chl[k] = dirL ? sh_a(chr[k]) : sh_b(chr[k]);
    }
    cvB[wv][lane] = cvr[15];
    __syncthreads();
    const float cvm1 = (wv == 0) ? 0.0f : cvB[wv - 1][lane];

    float* Tb0 = T0 + b * HW;
    float* Tb1 = T1 + b * HW;
    float* ypb = ypred + b * HW;
    const bool cok = (lane >= 8 && lane < 56 && gx0 + lane < 512);

    for (int t = 1; t <= 8; t++) {
        if (t == 1) {
            // transitive gate: row min(i+1,10) complete through block j+1
            if (tid == 0)
                poll_ge<8>(&rowflag[(b * 11 + min(i + 1, 10)) * 16], min(j + 2, 11));
        } else {
            if (tid < 9) {
                int di = tid / 3 - 1, dj = tid % 3 - 1;
                if (di != 0 || dj != 0) {
                    int ni = i + di, nj = j + dj;
                    if (ni >= 0 && ni < NBLKS && nj >= 0 && nj < NBLKS)
                        poll_ge<2>(&dflag[(b * 121 + ni * NBLKS + nj) * 16], t - 1);
                }
            }
        }
        __syncthreads();
        const float* src = (t == 1) ? Db : (((t - 1) & 1) ? Tb1 : Tb0);
        float u[16];
        #pragma unroll
        for (int k = 0; k < 16; k++) u[k] = ldc(&src[gyA[k] * W + gxc]);

        for (int it = 0; it < 8; it++) {
            xT[wv][lane] = u[0];
            xB[wv][lane] = u[15];
            __syncthreads();
            float ub = (wv > 0) ? xB[wv - 1][lane] : u[0];
            float ut = (wv < 3) ? xT[wv + 1][lane] : u[15];
            float V[16];
            #pragma unroll
            for (int k = 0; k < 16; k++) {
                float up = (k == 0) ? ub : u[k - 1];
                float dn = (k == 15) ? ut : u[k + 1];
                float cup = (k == 0) ? cvm1 : cvr[k - 1];
                V[k] = u[k] + LDIFF * cvr[k] * (dn - u[k]) - LDIFF * cup * (u[k] - up);
            }
            #pragma unroll
            for (int k = 0; k < 16; k++) {
                float rA = rot_a(V[k]);
                float rB = rot_b(V[k]);
                float lf = dirL ? rA : rB;
                float rt = dirL ? rB : rA;
                u[k] = V[k] + LDIFF * chr[k] * (rt - V[k]) - LDIFF * chl[k] * (V[k] - lf);
            }
            __syncthreads();
        }

        if (t < 8) {
            float* dst = (t & 1) ? Tb1 : Tb0;
            if (cok) {
                #pragma unroll
                for (int k = 0; k < 16; k++) {
                    int r = r0 + k;
                    if (r >= 8 && r < 56) {
                        int y = gy0 + r;
                        if (y < 512) stc(&dst[y * W + gx0 + lane], u[k]);
                    }
                }
            }
            asm volatile("s_waitcnt vmcnt(0)" ::: "memory");
            __syncthreads();
            if (tid == 0) stci(&dflag[me * 16], t);
        } else {
            if (cok) {
                #pragma unroll
                for (int k = 0; k < 16; k++) {
                    int r = r0 + k;
                    if (r >= 8 && r < 56) {
                        int y = gy0 + r;
                        if (y < 512) ypb[y * W + gx0 + lane] = u[k];
                    }
                }
            }
        }
    }
}

extern "C" void kernel_launch(void* const* d_in, const int* in_sizes, int n_in,
                              void* d_out, int out_size, void* d_ws, size_t ws_size,
                              hipStream_t stream) {
    const float* guide   = (const float*)d_in[0];
    const float* initial = (const float*)d_in[1];
    float* y_pred = (float*)d_out;
    float* cv = y_pred + N_D;          // output 1
    float* ch = cv + N_CV;             // output 2

    uint8_t* w = (uint8_t*)d_ws;
    int* sync_ = (int*)w;              // bar@0, rowflag@16, dflag@512, prmq@4608 (ints)
    float* D  = (float*)(w + 32768);
    float* T0 = (float*)(w + 32768 + (size_t)N_D * 4);
    float* T1 = (float*)(w + 32768 + (size_t)2 * N_D * 4);

    (void)hipMemsetAsync(sync_, 0, 28672, stream);
    kall<<<dim3(121, NB), 256, 0, stream>>>(guide, initial, cv, ch, D, T0, T1, y_pred, sync_);
}

// Round 9
// 322.065 us; speedup vs baseline: 1.3946x; 1.3946x over previous
//
#include <hip/hip_runtime.h>
#include <stdint.h>

#define LDIFF 0.24f

constexpr int H = 512, W = 512, NB = 2;
constexpr int HW = H * W;              // 2^18
constexpr int N_D = NB * HW;           // 524288
constexpr int CVH = 511, CVW = 512;
constexpr int CHH = 512, CHW = 511;
constexpr int N_CV = NB * CVH * CVW;   // 523264
constexpr int NBLKS = 11;              // 11x11 blocks, step 48
constexpr int NBT = NB * 121;          // 242 workgroups <= 256 CUs -> co-resident

// LLC-coherent (cross-XCD) access: relaxed agent atomics = sc1 ops through the
// Infinity Cache. Validated R4-R8.
__device__ inline float ldc(const float* p) {
    return __hip_atomic_load(p, __ATOMIC_RELAXED, __HIP_MEMORY_SCOPE_AGENT);
}
__device__ inline void stc(float* p, float v) {
    __hip_atomic_store(p, v, __ATOMIC_RELAXED, __HIP_MEMORY_SCOPE_AGENT);
}
__device__ inline int ldci(const int* p) {
    return __hip_atomic_load(p, __ATOMIC_RELAXED, __HIP_MEMORY_SCOPE_AGENT);
}
__device__ inline void stci(int* p, int v) {
    __hip_atomic_store(p, v, __ATOMIC_RELAXED, __HIP_MEMORY_SCOPE_AGENT);
}
template <int SLP>
__device__ inline void poll_ge(const int* p, int v) {
    while (ldci(p) < v) __builtin_amdgcn_s_sleep(SLP);
}

// wave64 DPP rotate/shift by 1 (VALU pipe, zero LDS traffic). Direction probed
// at runtime (dirL); the wavefront stencil's use (lf+rt) is direction-agnostic.
__device__ inline float rot_a(float x) {
    return __int_as_float(__builtin_amdgcn_update_dpp(0, __float_as_int(x), 0x134, 0xf, 0xf, false));
}
__device__ inline float rot_b(float x) {
    return __int_as_float(__builtin_amdgcn_update_dpp(0, __float_as_int(x), 0x13c, 0xf, 0xf, false));
}
__device__ inline float sh_a(float x) {
    return __int_as_float(__builtin_amdgcn_update_dpp(0, __float_as_int(x), 0x130, 0xf, 0xf, true));
}
__device__ inline float sh_b(float x) {
    return __int_as_float(__builtin_amdgcn_update_dpp(0, __float_as_int(x), 0x138, 0xf, 0xf, true));
}

// ======================= ONE kernel, zero global barriers =======================
// Per block (i,j,b):
//  A) local cv/ch halo tile (73x73) from guide into LDS; write disjoint 48x48
//     cv/ch output partition; params via wave-butterfly reduction.
//  B) wavefront: wait {(i,j-1),(i-1,j),(i-1,j+1)} flags; strips from D (sc1),
//     interior from `initial` (prefetched pre-wait); 10-iter periodic stencil
//     (1 barrier/iter, DPP horizontal); blend; write FULL tile to D; flag.
//     cond=false: write non-strip region from initial, no wait, flag.
//     (No D:=initial copy anywhere: every pixel's last writer writes it.)
//  C) diffusion 8 stages x 8 iters, 3x3 neighbor-flag chained, pipelines
//     behind the wavefront tail; cv/ch fragments straight from LDS.
__global__ __launch_bounds__(256) void kall(
    const float* __restrict__ guide, const float* __restrict__ initial,
    float* __restrict__ cv, float* __restrict__ ch,
    float* __restrict__ D, float* __restrict__ T0, float* __restrict__ T1,
    float* __restrict__ ypred, int* __restrict__ sync_)
{
    __shared__ float cvT[73 * 74];
    __shared__ float chT[73 * 74];
    __shared__ float xT[2][4][64];
    __shared__ float xB[2][4][64];
    __shared__ float red[12];
    __shared__ float prmS[3];

    int* wflag = sync_;                   // (b*121+blk)*16
    int* dflag = sync_ + 4096;            // (b*121+blk)*16

    const int blk = blockIdx.x;           // 0..120
    const int i = blk / NBLKS, j = blk % NBLKS;
    const int b = blockIdx.y;
    const int tid = threadIdx.x;
    const int lane = tid & 63, wv = tid >> 6;
    const int r0 = wv * 16;
    const int me = b * 121 + blk;

    const int y0 = i * 48, x0 = j * 48;
    const int y1 = min(y0 + 64, 512), x1 = min(x0 + 64, 512);
    const int bh = y1 - y0, bw = x1 - x0;
    const int yb = y0 - 8, xb = x0 - 8;
    const float kinv = 1.0f / (0.03f * 0.03f);

    // ===== A1: local cv/ch (rows yb..yb+72, cols xb..xb+72; 0 outside valid) =====
    const float* gb = guide + (size_t)b * 3 * HW;
    for (int p = tid; p < 73 * 73; p += 256) {
        int rr = p / 73, cc2 = p - rr * 73;
        int y = yb + rr, x = xb + cc2;
        float cvv = 0.0f, chv = 0.0f;
        if (y >= 0 && y < 512 && x >= 0 && x < 512) {
            const float* g = gb + y * W + x;
            float g0 = g[0], g1 = g[HW], g2 = g[2 * HW];
            if (y < 511) {
                float d = (fabsf(g[W] - g0) + fabsf(g[HW + W] - g1) + fabsf(g[2 * HW + W] - g2)) * (1.0f / 3.0f);
                cvv = 1.0f / (1.0f + d * d * kinv);
            }
            if (x < 511) {
                float d = (fabsf(g[1] - g0) + fabsf(g[HW + 1] - g1) + fabsf(g[2 * HW + 1] - g2)) * (1.0f / 3.0f);
                chv = 1.0f / (1.0f + d * d * kinv);
            }
        }
        cvT[rr * 74 + cc2] = cvv;
        chT[rr * 74 + cc2] = chv;
    }
    __syncthreads();

    // ===== A2: write disjoint cv/ch output partitions (48x48 cores) =====
    {
        int rcv = min(y0 + 48, CVH) - y0, ccv = min(x0 + 48, CVW) - x0;
        float* cvo = cv + b * CVH * CVW;
        for (int p = tid; p < rcv * ccv; p += 256) {
            int r = p / ccv, c = p - r * ccv;
            cvo[(y0 + r) * CVW + x0 + c] = cvT[(r + 8) * 74 + c + 8];
        }
        int rch = min(y0 + 48, CHH) - y0, cch = min(x0 + 48, CHW) - x0;
        float* cho = ch + b * CHH * CHW;
        for (int p = tid; p < rch * cch; p += 256) {
            int r = p / cch, c = p - r * cch;
            cho[(y0 + r) * CHW + x0 + c] = chT[(r + 8) * 74 + c + 8];
        }
    }

    // ===== A3: params (cv mean, ch mean, cond) — wave butterfly + 1 barrier =====
    float scv = 0.f, sch = 0.f, sun = 0.f;
    {
        int n = (bh - 1) * bw;
        for (int p = tid; p < n; p += 256) { int r = p / bw, c = p - r * bw; scv += cvT[(r + 8) * 74 + c + 8]; }
    }
    {
        int cols = bw - 1, n = bh * cols;
        for (int p = tid; p < n; p += 256) { int r = p / cols, c = p - r * cols; sch += chT[(r + 8) * 74 + c + 8]; }
    }
    const int ur = min(y1, 511) - y0, uc = min(x1, 511) - x0;
    {
        int n = ur * uc;
        for (int p = tid; p < n; p += 256) {
            int r = p / uc, c = p - r * uc;
            float s1 = 0.f, s2 = 0.f, t1 = 0.f, t2 = 0.f;
            #pragma unroll
            for (int dy = 0; dy < 3; dy++)
                #pragma unroll
                for (int dx = 0; dx < 3; dx++) {
                    float v = cvT[(r + 7 + dy) * 74 + c + 7 + dx]; s1 += v; s2 += v * v;
                    float w2 = chT[(r + 7 + dy) * 74 + c + 7 + dx]; t1 += w2; t2 += w2 * w2;
                }
            float m = s1 * (1.0f / 9.0f);
            float vcv = s2 * (1.0f / 9.0f) - m * m;
            m = t1 * (1.0f / 9.0f);
            float vch = t2 * (1.0f / 9.0f) - m * m;
            if (vcv < 0.1f && vch < 0.1f) sun += 1.f;
        }
    }
    #pragma unroll
    for (int m = 1; m < 64; m <<= 1) {
        scv += __shfl_xor(scv, m);
        sch += __shfl_xor(sch, m);
        sun += __shfl_xor(sun, m);
    }
    if (lane == 0) { red[wv * 3] = scv; red[wv * 3 + 1] = sch; red[wv * 3 + 2] = sun; }
    __syncthreads();
    if (tid == 0) {
        float a0 = red[0] + red[3] + red[6] + red[9];
        float a1 = red[1] + red[4] + red[7] + red[10];
        float a2 = red[2] + red[5] + red[8] + red[11];
        prmS[0] = a0 / (float)((bh - 1) * bw);
        prmS[1] = a1 / (float)(bh * (bw - 1));
        prmS[2] = (a2 / (float)(ur * uc) > 0.7f) ? 1.0f : 0.0f;
    }
    __syncthreads();

    // DPP direction probe (wave-uniform)
    int prb = __builtin_amdgcn_update_dpp(0, lane, 0x134, 0xf, 0xf, false);
    const bool dirL = (prb == ((lane + 63) & 63));

    const bool cond = prmS[2] > 0.5f;
    const float a = LDIFF * prmS[0], bc = LDIFF * prmS[1];
    float* Db = D + b * HW;
    const float* ini = initial + b * HW;

    // ===== B: wavefront =====
    const int mh = bh - 1, mw = bw - 1;
    const int ccw = lane & mw;

    if (!cond) {
        // region unchanged: write my non-strip region from `initial` (those
        // pixels' last writer is me and their value is untouched initial).
        #pragma unroll
        for (int k = 0; k < 16; k++) {
            int r = r0 + k;
            if (r < bh && (i == 0 || r >= 16) && lane < bw && (j == 0 || lane >= 16)) {
                int ad = (y0 + r) * W + x0 + lane;
                stc(&Db[ad], ini[ad]);
            }
        }
        asm volatile("s_waitcnt vmcnt(0)" ::: "memory");
        __syncthreads();
        if (tid == 0) stci(&wflag[me * 16], 1);
    } else {
        float u[16], orig[16];
        int addr[16]; bool fD[16];
        #pragma unroll
        for (int k = 0; k < 16; k++) {
            int rr = (r0 + k) & mh;
            addr[k] = (y0 + rr) * W + x0 + ccw;
            fD[k] = (i > 0 && rr < 16) || (j > 0 && ccw < 16);
            if (!fD[k]) orig[k] = ini[addr[k]];     // prefetch interior pre-wait
        }
        if (tid < 3) {
            int di = (tid == 0) ? i : i - 1;
            int dj = (tid == 0) ? j - 1 : ((tid == 1) ? j : j + 1);
            if (di >= 0 && dj >= 0 && dj < NBLKS)
                poll_ge<1>(&wflag[(b * 121 + di * NBLKS + dj) * 16], 1);
        }
        __syncthreads();
        #pragma unroll
        for (int k = 0; k < 16; k++) if (fD[k]) orig[k] = ldc(&Db[addr[k]]);
        #pragma unroll
        for (int k = 0; k < 16; k++) u[k] = orig[k];

        int bs = 0;
        for (int it = 0; it < 10; it++) {
            xT[bs][wv][lane] = u[0];
            xB[bs][wv][lane] = u[15];
            __syncthreads();
            float ub = xB[bs][(wv + 3) & 3][lane];   // row r0-1 (periodic)
            float ut = xT[bs][(wv + 1) & 3][lane];   // row r0+16 (periodic)
            float nu[16];
            #pragma unroll
            for (int k = 0; k < 16; k++) {
                float up = (k == 0) ? ub : u[k - 1];
                float dn = (k == 15) ? ut : u[k + 1];
                float hsum = rot_a(u[k]) + rot_b(u[k]);
                nu[k] = u[k] + a * (up + dn - 2.0f * u[k]) + bc * (hsum - 2.0f * u[k]);
            }
            #pragma unroll
            for (int k = 0; k < 16; k++) u[k] = nu[k];
            bs ^= 1;
        }

        #pragma unroll
        for (int k = 0; k < 16; k++) {
            int r = r0 + k;
            if (r < bh && lane < bw) {
                int rr = r;   // r < bh so (r & mh) == r
                float byw = (y0 > 0 && rr < 16) ? (float)rr * (1.0f / 16.0f) : 1.0f;
                float bxw = (x0 > 0 && lane < 16) ? (float)lane * (1.0f / 16.0f) : 1.0f;
                float wgt = byw * bxw;
                stc(&Db[(y0 + r) * W + x0 + lane], orig[k] * (1.0f - wgt) + u[k] * wgt);
            }
        }
        asm volatile("s_waitcnt vmcnt(0)" ::: "memory");
        __syncthreads();
        if (tid == 0) stci(&wflag[me * 16], 1);
    }

    // ===== C: diffusion, 8 stages x 8 iters, neighbor-flag chained =====
    const int cx = xb + lane;
    const int gxc = min(max(cx, 0), 511);
    float cvr[16], chr[16], chl[16];
    int gyA[16];
    #pragma unroll
    for (int k = 0; k < 16; k++) {
        int cy = yb + r0 + k;
        gyA[k] = min(max(cy, 0), 511);
        cvr[k] = cvT[(r0 + k) * 74 + lane];    // 0 outside valid by construction
        chr[k] = chT[(r0 + k) * 74 + lane];
        chl[k] = dirL ? sh_a(chr[k]) : sh_b(chr[k]);   // lane0 -> 0 (halo col)
    }
    const float cvm1 = (wv == 0) ? 0.0f : cvT[(r0 - 1) * 74 + lane];

    float* Tb0 = T0 + b * HW;
    float* Tb1 = T1 + b * HW;
    float* ypb = ypred + b * HW;
    const bool cok = (lane >= 8 && lane < 56 && xb + lane < 512);

    for (int t = 1; t <= 8; t++) {
        if (tid < 9) {
            int di = tid / 3 - 1, dj = tid % 3 - 1;
            int ni = i + di, nj = j + dj;
            if (ni >= 0 && ni < NBLKS && nj >= 0 && nj < NBLKS && (di | dj) != 0) {
                int nb = (b * 121 + ni * NBLKS + nj) * 16;
                if (t == 1) poll_ge<2>(&wflag[nb], 1);
                else        poll_ge<2>(&dflag[nb], t - 1);
            }
        }
        if (t == 1 && tid == 9) poll_ge<2>(&wflag[me * 16], 1);   // self (cond=false path wrote D)
        __syncthreads();
        const float* src = (t == 1) ? Db : (((t - 1) & 1) ? Tb1 : Tb0);
        float u[16];
        #pragma unroll
        for (int k = 0; k < 16; k++) u[k] = ldc(&src[gyA[k] * W + gxc]);

        int bs = 0;
        for (int it = 0; it < 8; it++) {
            xT[bs][wv][lane] = u[0];
            xB[bs][wv][lane] = u[15];
            __syncthreads();
            float ub = (wv > 0) ? xB[bs][wv - 1][lane] : u[0];
            float ut = (wv < 3) ? xT[bs][wv + 1][lane] : u[15];
            float V[16];
            #pragma unroll
            for (int k = 0; k < 16; k++) {
                float up = (k == 0) ? ub : u[k - 1];
                float dn = (k == 15) ? ut : u[k + 1];
                float cup = (k == 0) ? cvm1 : cvr[k - 1];
                V[k] = u[k] + LDIFF * cvr[k] * (dn - u[k]) - LDIFF * cup * (u[k] - up);
            }
            #pragma unroll
            for (int k = 0; k < 16; k++) {
                float rA = rot_a(V[k]);
                float rB = rot_b(V[k]);
                float lf = dirL ? rA : rB;
                float rt = dirL ? rB : rA;
                u[k] = V[k] + LDIFF * chr[k] * (rt - V[k]) - LDIFF * chl[k] * (V[k] - lf);
            }
            bs ^= 1;
        }

        if (t < 8) {
            float* dst = (t & 1) ? Tb1 : Tb0;
            if (cok) {
                #pragma unroll
                for (int k = 0; k < 16; k++) {
                    int r = r0 + k;
                    if (r >= 8 && r < 56) {
                        int y = yb + r;
                        if (y < 512) stc(&dst[y * W + xb + lane], u[k]);
                    }
                }
            }
            asm volatile("s_waitcnt vmcnt(0)" ::: "memory");
            __syncthreads();
            if (tid == 0) stci(&dflag[me * 16], t);
        } else {
            if (cok) {
                #pragma unroll
                for (int k = 0; k < 16; k++) {
                    int r = r0 + k;
                    if (r >= 8 && r < 56) {
                        int y = yb + r;
                        if (y < 512) ypb[y * W + xb + lane] = u[k];
                    }
                }
            }
        }
    }
}

extern "C" void kernel_launch(void* const* d_in, const int* in_sizes, int n_in,
                              void* d_out, int out_size, void* d_ws, size_t ws_size,
                              hipStream_t stream) {
    const float* guide   = (const float*)d_in[0];
    const float* initial = (const float*)d_in[1];
    float* y_pred = (float*)d_out;
    float* cv = y_pred + N_D;          // output 1
    float* ch = cv + N_CV;             // output 2

    uint8_t* w = (uint8_t*)d_ws;
    int* sync_ = (int*)w;              // wflag @0, dflag @4096 (ints)
    float* D  = (float*)(w + 32768);
    float* T0 = (float*)(w + 32768 + (size_t)N_D * 4);
    float* T1 = (float*)(w + 32768 + (size_t)2 * N_D * 4);

    (void)hipMemsetAsync(sync_, 0, 32768, stream);
    kall<<<dim3(121, NB), 256, 0, stream>>>(guide, initial, cv, ch, D, T0, T1, y_pred, sync_);
}

// Round 10
// 321.907 us; speedup vs baseline: 1.3952x; 1.0005x over previous
//
#include <hip/hip_runtime.h>
#include <stdint.h>

#define LDIFF 0.24f

constexpr int H = 512, W = 512, NB = 2;
constexpr int HW = H * W;              // 2^18
constexpr int N_D = NB * HW;           // 524288
constexpr int CVH = 511, CVW = 512;
constexpr int CHH = 512, CHW = 511;
constexpr int N_CV = NB * CVH * CVW;   // 523264
constexpr int NBLKS = 11;              // 11x11 blocks, step 48
constexpr int NBT = NB * 121;          // 242 workgroups <= 256 CUs -> co-resident

// LLC-coherent (cross-XCD) access: relaxed agent atomics = sc1 ops through the
// Infinity Cache. Validated R4-R9.
__device__ inline float ldc(const float* p) {
    return __hip_atomic_load(p, __ATOMIC_RELAXED, __HIP_MEMORY_SCOPE_AGENT);
}
__device__ inline void stc(float* p, float v) {
    __hip_atomic_store(p, v, __ATOMIC_RELAXED, __HIP_MEMORY_SCOPE_AGENT);
}
__device__ inline int ldci(const int* p) {
    return __hip_atomic_load(p, __ATOMIC_RELAXED, __HIP_MEMORY_SCOPE_AGENT);
}
__device__ inline void stci(int* p, int v) {
    __hip_atomic_store(p, v, __ATOMIC_RELAXED, __HIP_MEMORY_SCOPE_AGENT);
}

// wave64 DPP rotate/shift by 1 (VALU pipe, zero LDS traffic). Direction probed
// at runtime (dirL); the wavefront stencil's use (lf+rt) is direction-agnostic.
__device__ inline float rot_a(float x) {
    return __int_as_float(__builtin_amdgcn_update_dpp(0, __float_as_int(x), 0x134, 0xf, 0xf, false));
}
__device__ inline float rot_b(float x) {
    return __int_as_float(__builtin_amdgcn_update_dpp(0, __float_as_int(x), 0x13c, 0xf, 0xf, false));
}
__device__ inline float sh_a(float x) {
    return __int_as_float(__builtin_amdgcn_update_dpp(0, __float_as_int(x), 0x130, 0xf, 0xf, true));
}
__device__ inline float sh_b(float x) {
    return __int_as_float(__builtin_amdgcn_update_dpp(0, __float_as_int(x), 0x138, 0xf, 0xf, true));
}

// ======================= ONE kernel, zero global barriers =======================
//  A) local cv/ch halo tile (73x73) into LDS; write disjoint cv/ch partition;
//     params via wave butterfly.
//  B) wavefront: per-WAVE producer sub-flags (each wave drains own stores, no
//     producer barrier); consumer = wave0 single-load ballot poll of 6 dep
//     sub-flags (L.w1-3, U.w3, UR.w3, UL.w3); 10-iter periodic stencil.
//  C) diffusion 8 stages x 8 iters, 3x3 neighbor chained, throttled polls.
__global__ __launch_bounds__(256) void kall(
    const float* __restrict__ guide, const float* __restrict__ initial,
    float* __restrict__ cv, float* __restrict__ ch,
    float* __restrict__ D, float* __restrict__ T0, float* __restrict__ T1,
    float* __restrict__ ypred, int* __restrict__ sync_)
{
    __shared__ float cvT[73 * 74];
    __shared__ float chT[73 * 74];
    __shared__ float xT[2][4][64];
    __shared__ float xB[2][4][64];
    __shared__ float red[12];
    __shared__ float prmS[3];

    int* wflag = sync_;                   // (b*121+blk)*64 + wave*16
    int* dflag = sync_ + 16384;           // (b*121+blk)*16

    const int blk = blockIdx.x;           // 0..120
    const int i = blk / NBLKS, j = blk % NBLKS;
    const int b = blockIdx.y;
    const int tid = threadIdx.x;
    const int lane = tid & 63, wv = tid >> 6;
    const int r0 = wv * 16;
    const int me = b * 121 + blk;

    const int y0 = i * 48, x0 = j * 48;
    const int y1 = min(y0 + 64, 512), x1 = min(x0 + 64, 512);
    const int bh = y1 - y0, bw = x1 - x0;
    const int yb = y0 - 8, xb = x0 - 8;
    const float kinv = 1.0f / (0.03f * 0.03f);

    // ===== A1: local cv/ch (rows yb..yb+72, cols xb..xb+72; 0 outside valid) =====
    const float* gb = guide + (size_t)b * 3 * HW;
    for (int p = tid; p < 73 * 73; p += 256) {
        int rr = p / 73, cc2 = p - rr * 73;
        int y = yb + rr, x = xb + cc2;
        float cvv = 0.0f, chv = 0.0f;
        if (y >= 0 && y < 512 && x >= 0 && x < 512) {
            const float* g = gb + y * W + x;
            float g0 = g[0], g1 = g[HW], g2 = g[2 * HW];
            if (y < 511) {
                float d = (fabsf(g[W] - g0) + fabsf(g[HW + W] - g1) + fabsf(g[2 * HW + W] - g2)) * (1.0f / 3.0f);
                cvv = 1.0f / (1.0f + d * d * kinv);
            }
            if (x < 511) {
                float d = (fabsf(g[1] - g0) + fabsf(g[HW + 1] - g1) + fabsf(g[2 * HW + 1] - g2)) * (1.0f / 3.0f);
                chv = 1.0f / (1.0f + d * d * kinv);
            }
        }
        cvT[rr * 74 + cc2] = cvv;
        chT[rr * 74 + cc2] = chv;
    }
    __syncthreads();

    // ===== A2: write disjoint cv/ch output partitions (48x48 cores) =====
    {
        int rcv = min(y0 + 48, CVH) - y0, ccv = min(x0 + 48, CVW) - x0;
        float* cvo = cv + b * CVH * CVW;
        for (int p = tid; p < rcv * ccv; p += 256) {
            int r = p / ccv, c = p - r * ccv;
            cvo[(y0 + r) * CVW + x0 + c] = cvT[(r + 8) * 74 + c + 8];
        }
        int rch = min(y0 + 48, CHH) - y0, cch = min(x0 + 48, CHW) - x0;
        float* cho = ch + b * CHH * CHW;
        for (int p = tid; p < rch * cch; p += 256) {
            int r = p / cch, c = p - r * cch;
            cho[(y0 + r) * CHW + x0 + c] = chT[(r + 8) * 74 + c + 8];
        }
    }

    // ===== A3: params — wave butterfly + 1 barrier =====
    float scv = 0.f, sch = 0.f, sun = 0.f;
    {
        int n = (bh - 1) * bw;
        for (int p = tid; p < n; p += 256) { int r = p / bw, c = p - r * bw; scv += cvT[(r + 8) * 74 + c + 8]; }
    }
    {
        int cols = bw - 1, n = bh * cols;
        for (int p = tid; p < n; p += 256) { int r = p / cols, c = p - r * cols; sch += chT[(r + 8) * 74 + c + 8]; }
    }
    const int ur = min(y1, 511) - y0, uc = min(x1, 511) - x0;
    {
        int n = ur * uc;
        for (int p = tid; p < n; p += 256) {
            int r = p / uc, c = p - r * uc;
            float s1 = 0.f, s2 = 0.f, t1 = 0.f, t2 = 0.f;
            #pragma unroll
            for (int dy = 0; dy < 3; dy++)
                #pragma unroll
                for (int dx = 0; dx < 3; dx++) {
                    float v = cvT[(r + 7 + dy) * 74 + c + 7 + dx]; s1 += v; s2 += v * v;
                    float w2 = chT[(r + 7 + dy) * 74 + c + 7 + dx]; t1 += w2; t2 += w2 * w2;
                }
            float m = s1 * (1.0f / 9.0f);
            float vcv = s2 * (1.0f / 9.0f) - m * m;
            m = t1 * (1.0f / 9.0f);
            float vch = t2 * (1.0f / 9.0f) - m * m;
            if (vcv < 0.1f && vch < 0.1f) sun += 1.f;
        }
    }
    #pragma unroll
    for (int m = 1; m < 64; m <<= 1) {
        scv += __shfl_xor(scv, m);
        sch += __shfl_xor(sch, m);
        sun += __shfl_xor(sun, m);
    }
    if (lane == 0) { red[wv * 3] = scv; red[wv * 3 + 1] = sch; red[wv * 3 + 2] = sun; }
    __syncthreads();
    if (tid == 0) {
        float a0 = red[0] + red[3] + red[6] + red[9];
        float a1 = red[1] + red[4] + red[7] + red[10];
        float a2 = red[2] + red[5] + red[8] + red[11];
        prmS[0] = a0 / (float)((bh - 1) * bw);
        prmS[1] = a1 / (float)(bh * (bw - 1));
        prmS[2] = (a2 / (float)(ur * uc) > 0.7f) ? 1.0f : 0.0f;
    }
    __syncthreads();

    // DPP direction probe (wave-uniform)
    int prb = __builtin_amdgcn_update_dpp(0, lane, 0x134, 0xf, 0xf, false);
    const bool dirL = (prb == ((lane + 63) & 63));

    const bool cond = prmS[2] > 0.5f;
    const float a = LDIFF * prmS[0], bc = LDIFF * prmS[1];
    float* Db = D + b * HW;
    const float* ini = initial + b * HW;

    // ===== B: wavefront =====
    const int mh = bh - 1, mw = bw - 1;
    const int ccw = lane & mw;

    if (!cond) {
        // region unchanged: write my non-strip region from `initial`
        #pragma unroll
        for (int k = 0; k < 16; k++) {
            int r = r0 + k;
            if (r < bh && (i == 0 || r >= 16) && lane < bw && (j == 0 || lane >= 16)) {
                int ad = (y0 + r) * W + x0 + lane;
                stc(&Db[ad], ini[ad]);
            }
        }
        asm volatile("s_waitcnt vmcnt(0)" ::: "memory");
        if (lane == 0) stci(&wflag[me * 64 + wv * 16], 1);
    } else {
        float u[16], orig[16];
        int addr[16]; bool fD[16];
        #pragma unroll
        for (int k = 0; k < 16; k++) {
            int rr = (r0 + k) & mh;
            addr[k] = (y0 + rr) * W + x0 + ccw;
            fD[k] = (i > 0 && rr < 16) || (j > 0 && ccw < 16);
            if (!fD[k]) orig[k] = ini[addr[k]];     // prefetch interior pre-wait
        }
        // ---- ballot poll: 6 dep sub-flags, one load instr per iteration ----
        if (wv == 0) {
            bool need = false;
            const int* fp = &wflag[me * 64];
            if (lane < 3) {
                if (j > 0) { need = true; fp = &wflag[(b * 121 + i * NBLKS + j - 1) * 64 + (lane + 1) * 16]; }
            } else if (lane == 3) {
                if (i > 0) { need = true; fp = &wflag[(b * 121 + (i - 1) * NBLKS + j) * 64 + 3 * 16]; }
            } else if (lane == 4) {
                if (i > 0 && j < 10) { need = true; fp = &wflag[(b * 121 + (i - 1) * NBLKS + j + 1) * 64 + 3 * 16]; }
            } else if (lane == 5) {
                if (i > 0 && j > 0) { need = true; fp = &wflag[(b * 121 + (i - 1) * NBLKS + j - 1) * 64 + 3 * 16]; }
            }
            while (true) {
                int v = need ? ldci(fp) : 1;
                if (__ballot(v == 0) == 0) break;
                __builtin_amdgcn_s_sleep(0);
            }
        }
        __syncthreads();
        #pragma unroll
        for (int k = 0; k < 16; k++) if (fD[k]) orig[k] = ldc(&Db[addr[k]]);
        #pragma unroll
        for (int k = 0; k < 16; k++) u[k] = orig[k];

        int bs = 0;
        for (int it = 0; it < 10; it++) {
            xT[bs][wv][lane] = u[0];
            xB[bs][wv][lane] = u[15];
            __syncthreads();
            float ub = xB[bs][(wv + 3) & 3][lane];   // row r0-1 (periodic)
            float ut = xT[bs][(wv + 1) & 3][lane];   // row r0+16 (periodic)
            float nu[16];
            #pragma unroll
            for (int k = 0; k < 16; k++) {
                float up = (k == 0) ? ub : u[k - 1];
                float dn = (k == 15) ? ut : u[k + 1];
                float hsum = rot_a(u[k]) + rot_b(u[k]);
                nu[k] = u[k] + a * (up + dn - 2.0f * u[k]) + bc * (hsum - 2.0f * u[k]);
            }
            #pragma unroll
            for (int k = 0; k < 16; k++) u[k] = nu[k];
            bs ^= 1;
        }

        #pragma unroll
        for (int k = 0; k < 16; k++) {
            int r = r0 + k;
            if (r < bh && lane < bw) {
                float byw = (y0 > 0 && r < 16) ? (float)r * (1.0f / 16.0f) : 1.0f;
                float bxw = (x0 > 0 && lane < 16) ? (float)lane * (1.0f / 16.0f) : 1.0f;
                float wgt = byw * bxw;
                stc(&Db[(y0 + r) * W + x0 + lane], orig[k] * (1.0f - wgt) + u[k] * wgt);
            }
        }
        asm volatile("s_waitcnt vmcnt(0)" ::: "memory");   // per-wave drain of own stores
        if (lane == 0) stci(&wflag[me * 64 + wv * 16], 1); // per-wave publish
    }
    __syncthreads();   // all waves published; own D region complete for phase C

    // ===== C: diffusion, 8 stages x 8 iters, neighbor-flag chained =====
    const int cx = xb + lane;
    const int gxc = min(max(cx, 0), 511);
    float cvr[16], chr[16], chl[16];
    int gyA[16];
    #pragma unroll
    for (int k = 0; k < 16; k++) {
        int cy = yb + r0 + k;
        gyA[k] = min(max(cy, 0), 511);
        cvr[k] = cvT[(r0 + k) * 74 + lane];    // 0 outside valid by construction
        chr[k] = chT[(r0 + k) * 74 + lane];
        chl[k] = dirL ? sh_a(chr[k]) : sh_b(chr[k]);   // lane0 -> 0 (halo col)
    }
    const float cvm1 = (wv == 0) ? 0.0f : cvT[(r0 - 1) * 74 + lane];

    float* Tb0 = T0 + b * HW;
    float* Tb1 = T1 + b * HW;
    float* ypb = ypred + b * HW;
    const bool cok = (lane >= 8 && lane < 56 && xb + lane < 512);

    for (int t = 1; t <= 8; t++) {
        if (wv == 0) {
            bool need = false;
            const int* fp = &wflag[me * 64];
            int thr = 1;
            if (t == 1) {
                if (lane < 36) {
                    int nb = lane >> 2;
                    int di = nb / 3 - 1, dj = nb % 3 - 1;
                    int ni = i + di, nj = j + dj;
                    if ((di | dj) != 0 && ni >= 0 && ni < NBLKS && nj >= 0 && nj < NBLKS) {
                        need = true;
                        fp = &wflag[(b * 121 + ni * NBLKS + nj) * 64 + (lane & 3) * 16];
                    }
                }
            } else {
                thr = t - 1;
                if (lane < 9) {
                    int di = lane / 3 - 1, dj = lane % 3 - 1;
                    int ni = i + di, nj = j + dj;
                    if ((di | dj) != 0 && ni >= 0 && ni < NBLKS && nj >= 0 && nj < NBLKS) {
                        need = true;
                        fp = &dflag[(b * 121 + ni * NBLKS + nj) * 16];
                    }
                }
            }
            while (true) {
                int v = need ? ldci(fp) : 0x7fffffff;
                if (__ballot(v < thr) == 0) break;
                __builtin_amdgcn_s_sleep(8);
            }
        }
        __syncthreads();
        const float* src = (t == 1) ? Db : (((t - 1) & 1) ? Tb1 : Tb0);
        float u[16];
        #pragma unroll
        for (int k = 0; k < 16; k++) u[k] = ldc(&src[gyA[k] * W + gxc]);

        int bs = 0;
        for (int it = 0; it < 8; it++) {
            xT[bs][wv][lane] = u[0];
            xB[bs][wv][lane] = u[15];
            __syncthreads();
            float ub = (wv > 0) ? xB[bs][wv - 1][lane] : u[0];
            float ut = (wv < 3) ? xT[bs][wv + 1][lane] : u[15];
            float V[16];
            #pragma unroll
            for (int k = 0; k < 16; k++) {
                float up = (k == 0) ? ub : u[k - 1];
                float dn = (k == 15) ? ut : u[k + 1];
                float cup = (k == 0) ? cvm1 : cvr[k - 1];
                V[k] = u[k] + LDIFF * cvr[k] * (dn - u[k]) - LDIFF * cup * (u[k] - up);
            }
            #pragma unroll
            for (int k = 0; k < 16; k++) {
                float rA = rot_a(V[k]);
                float rB = rot_b(V[k]);
                float lf = dirL ? rA : rB;
                float rt = dirL ? rB : rA;
                u[k] = V[k] + LDIFF * chr[k] * (rt - V[k]) - LDIFF * chl[k] * (V[k] - lf);
            }
            bs ^= 1;
        }

        if (t < 8) {
            float* dst = (t & 1) ? Tb1 : Tb0;
            if (cok) {
                #pragma unroll
                for (int k = 0; k < 16; k++) {
                    int r = r0 + k;
                    if (r >= 8 && r < 56) {
                        int y = yb + r;
                        if (y < 512) stc(&dst[y * W + xb + lane], u[k]);
                    }
                }
            }
            asm volatile("s_waitcnt vmcnt(0)" ::: "memory");
            __syncthreads();
            if (tid == 0) stci(&dflag[me * 16], t);
        } else {
            if (cok) {
                #pragma unroll
                for (int k = 0; k < 16; k++) {
                    int r = r0 + k;
                    if (r >= 8 && r < 56) {
                        int y = yb + r;
                        if (y < 512) ypb[y * W + xb + lane] = u[k];
                    }
                }
            }
        }
    }
}

extern "C" void kernel_launch(void* const* d_in, const int* in_sizes, int n_in,
                              void* d_out, int out_size, void* d_ws, size_t ws_size,
                              hipStream_t stream) {
    const float* guide   = (const float*)d_in[0];
    const float* initial = (const float*)d_in[1];
    float* y_pred = (float*)d_out;
    float* cv = y_pred + N_D;          // output 1
    float* ch = cv + N_CV;             // output 2

    uint8_t* w = (uint8_t*)d_ws;
    int* sync_ = (int*)w;              // wflag @0 (242*64 ints), dflag @16384 ints
    float* D  = (float*)(w + 131072);
    float* T0 = (float*)(w + 131072 + (size_t)N_D * 4);
    float* T1 = (float*)(w + 131072 + (size_t)2 * N_D * 4);

    (void)hipMemsetAsync(sync_, 0, 131072, stream);
    kall<<<dim3(121, NB), 256, 0, stream>>>(guide, initial, cv, ch, D, T0, T1, y_pred, sync_);
}